// Round 1
// baseline (269.058 us; speedup 1.0000x reference)
//
#include <hip/hip_runtime.h>
#include <hip/hip_bf16.h>

typedef __bf16 bf16x8 __attribute__((ext_vector_type(8)));
typedef float f32x4 __attribute__((ext_vector_type(4)));

#define MT 64   // tokens per block
#define CC 256

// swizzled LDS byte offset for element (r, c) of a [MT][256] bf16 tile:
// row stride 512B, XOR bits 4-6 with row&7 -> ds_read_b128 A-frags are 2-way (free)
__device__ __forceinline__ int swz(int r, int c) {
    return r * 512 + ((c * 2) ^ ((r & 7) << 4));
}

__device__ __forceinline__ void zero_acc(f32x4 acc[4][4]) {
#pragma unroll
    for (int i = 0; i < 4; ++i)
#pragma unroll
        for (int j = 0; j < 4; ++j)
            acc[i][j] = (f32x4){0.f, 0.f, 0.f, 0.f};
}

// Per-wave 64x64 GEMM tile: A from swizzled LDS [64][256] (k range a_k0+32*NKS),
// B from global transposed weights WT[N][wK] (k range b_k0+32*NKS), cols colbase..+63.
template<int NKS>
__device__ __forceinline__ void mfma_block(const __bf16* A_lds, const __bf16* WT, int wK,
                                           int colbase, int a_k0, int b_k0,
                                           f32x4 acc[4][4], int r16, int q4)
{
#pragma unroll
    for (int ks = 0; ks < NKS; ++ks) {
        int ak = a_k0 + ks * 32 + q4 * 8;
        int bk = b_k0 + ks * 32 + q4 * 8;
        bf16x8 a[4], b[4];
#pragma unroll
        for (int mf = 0; mf < 4; ++mf) {
            int r = mf * 16 + r16;
            a[mf] = *(const bf16x8*)((const char*)A_lds + swz(r, ak));
        }
#pragma unroll
        for (int nf = 0; nf < 4; ++nf) {
            int col = colbase + nf * 16 + r16;
            b[nf] = *(const bf16x8*)(WT + (size_t)col * wK + bk);
        }
#pragma unroll
        for (int mf = 0; mf < 4; ++mf)
#pragma unroll
            for (int nf = 0; nf < 4; ++nf)
                acc[mf][nf] = __builtin_amdgcn_mfma_f32_16x16x32_bf16(a[mf], b[nf], acc[mf][nf], 0, 0, 0);
    }
}

// transpose + convert weights: dst[n*K+k] = (bf16)src[k*N+n]
__global__ void prep_wt(const float* __restrict__ src, __bf16* __restrict__ dst, int K, int N) {
    int i = blockIdx.x * 256 + threadIdx.x;
    if (i >= K * N) return;
    int n = i / K, k = i - n * K;
    dst[i] = (__bf16)src[(size_t)k * N + n];
}

extern "C" __global__ void __launch_bounds__(256, 1)
fused_ext_attn(const float* __restrict__ query, const float* __restrict__ key,
               const float* __restrict__ value, const float* __restrict__ refp,
               const float* __restrict__ pose,
               const __bf16* __restrict__ WTq, const __bf16* __restrict__ WTk,
               const __bf16* __restrict__ WTv, const __bf16* __restrict__ WTpos,
               const __bf16* __restrict__ WTo1, const __bf16* __restrict__ WTo2,
               const __bf16* __restrict__ WTout,
               const float* __restrict__ bq, const float* __restrict__ bk,
               const float* __restrict__ bv, const float* __restrict__ bpos,
               const float* __restrict__ bo1, const float* __restrict__ bo2,
               const float* __restrict__ bout,
               float* __restrict__ out)
{
    __shared__ __attribute__((aligned(16))) __bf16 Ab[MT * CC];   // staging (pos_embed/query/key/value)
    __shared__ __attribute__((aligned(16))) __bf16 Pb[MT * CC];   // pos, then k+pos (in place)
    __shared__ __attribute__((aligned(16))) __bf16 Qb[MT * CC];   // q+pos
    __shared__ __attribute__((aligned(16))) __bf16 Hb[MT * CC];   // h1 pass buffer, then o = v*wv
    __shared__ float off_s[MT * 64];                              // offsets [t][h*8+k*2+xy]
    __shared__ float wv_s[MT * 8];                                // wv [t][h]

    const int tid = threadIdx.x;
    const int lane = tid & 63;
    const int wid = tid >> 6;
    const int r16 = lane & 15;
    const int q4 = lane >> 4;
    const int row0 = blockIdx.x * MT;
    const int cb = wid * 64;   // this wave's output-column base for N=256 phases

    // init offset accumulator with bo2
    for (int i = tid; i < MT * 64; i += 256) off_s[i] = bo2[i & 63];

    auto stage = [&](const float* __restrict__ src) {
#pragma unroll
        for (int i = 0; i < 16; ++i) {
            int f = i * 256 + tid;
            int r = f >> 6;
            int c = (f & 63) * 4;
            float4 v = *(const float4*)(src + (size_t)(row0 + r) * CC + c);
            union { __bf16 h[4]; unsigned long long u; } uu;
            uu.h[0] = (__bf16)v.x; uu.h[1] = (__bf16)v.y;
            uu.h[2] = (__bf16)v.z; uu.h[3] = (__bf16)v.w;
            *(unsigned long long*)((char*)Ab + swz(r, c)) = uu.u;
        }
    };

    f32x4 acc[4][4];

    // ---------- phase 1: pos = pos_embed @ Wpos + bpos ----------
    stage(pose);
    __syncthreads();
    zero_acc(acc);
    mfma_block<8>(Ab, WTpos, 256, cb, 0, 0, acc, r16, q4);
#pragma unroll
    for (int mf = 0; mf < 4; ++mf)
#pragma unroll
        for (int nf = 0; nf < 4; ++nf) {
            int col = cb + nf * 16 + r16;
            float bias = bpos[col];
#pragma unroll
            for (int r = 0; r < 4; ++r) {
                int row = mf * 16 + q4 * 4 + r;
                *(__bf16*)((char*)Pb + swz(row, col)) = (__bf16)(acc[mf][nf][r] + bias);
            }
        }
    __syncthreads();

    // ---------- phase 2: q = query @ Wq + bq + pos ----------
    stage(query);
    __syncthreads();
    zero_acc(acc);
    mfma_block<8>(Ab, WTq, 256, cb, 0, 0, acc, r16, q4);
#pragma unroll
    for (int mf = 0; mf < 4; ++mf)
#pragma unroll
        for (int nf = 0; nf < 4; ++nf) {
            int col = cb + nf * 16 + r16;
            float bias = bq[col];
#pragma unroll
            for (int r = 0; r < 4; ++r) {
                int row = mf * 16 + q4 * 4 + r;
                float pv = (float)*(const __bf16*)((const char*)Pb + swz(row, col));
                *(__bf16*)((char*)Qb + swz(row, col)) = (__bf16)(acc[mf][nf][r] + bias + pv);
            }
        }

    // ---------- phases 3/4: h1 = relu(query@Wo1+bo1) in two 256-col passes,
    //            off += relu_h1 @ Wo2 (K split across waves, serialized adds) ----------
    for (int p = 0; p < 2; ++p) {
        zero_acc(acc);
        mfma_block<8>(Ab, WTo1, 256, p * 256 + cb, 0, 0, acc, r16, q4);
#pragma unroll
        for (int mf = 0; mf < 4; ++mf)
#pragma unroll
            for (int nf = 0; nf < 4; ++nf) {
                int gcol = p * 256 + cb + nf * 16 + r16;
                int lcol = cb + nf * 16 + r16;
                float bias = bo1[gcol];
#pragma unroll
                for (int r = 0; r < 4; ++r) {
                    int row = mf * 16 + q4 * 4 + r;
                    float v = fmaxf(acc[mf][nf][r] + bias, 0.f);
                    *(__bf16*)((char*)Hb + swz(row, lcol)) = (__bf16)v;
                }
            }
        __syncthreads();   // Hb pass visible to off-GEMM K-slices
        zero_acc(acc);
        mfma_block<2>(Hb, WTo2, 512, 0, cb, p * 256 + cb, acc, r16, q4);
        for (int t = 0; t < 4; ++t) {   // serialize cross-wave accumulation into off_s
            if (wid == t) {
#pragma unroll
                for (int mf = 0; mf < 4; ++mf)
#pragma unroll
                    for (int nf = 0; nf < 4; ++nf) {
                        int col = nf * 16 + r16;
#pragma unroll
                        for (int r = 0; r < 4; ++r)
                            off_s[(mf * 16 + q4 * 4 + r) * 64 + col] += acc[mf][nf][r];
                    }
            }
            __syncthreads();
        }
    }

    // ---------- phase 5: k = key @ Wk + bk + pos  (in place into Pb) ----------
    stage(key);
    __syncthreads();
    zero_acc(acc);
    mfma_block<8>(Ab, WTk, 256, cb, 0, 0, acc, r16, q4);
#pragma unroll
    for (int mf = 0; mf < 4; ++mf)
#pragma unroll
        for (int nf = 0; nf < 4; ++nf) {
            int col = cb + nf * 16 + r16;
            float bias = bk[col];
#pragma unroll
            for (int r = 0; r < 4; ++r) {
                int row = mf * 16 + q4 * 4 + r;
                __bf16* pp = (__bf16*)((char*)Pb + swz(row, col));
                *pp = (__bf16)(acc[mf][nf][r] + bias + (float)*pp);
            }
        }
    __syncthreads();

    // ---------- attention scalar phase: 512 (token,head) pairs, 2 per thread ----------
#pragma unroll
    for (int pi = 0; pi < 2; ++pi) {
        int idx = tid + pi * 256;
        int t = idx >> 3, h = idx & 7;
        float qk = 0.f;
#pragma unroll
        for (int j = 0; j < 4; ++j) {
            int c = h * 32 + j * 8;
            bf16x8 qv = *(const bf16x8*)((const char*)Qb + swz(t, c));
            bf16x8 kv = *(const bf16x8*)((const char*)Pb + swz(t, c));
#pragma unroll
            for (int e = 0; e < 8; ++e) qk += (float)qv[e] * (float)kv[e];
        }
        float2 rp = *(const float2*)(refp + (size_t)(row0 + t) * 2);
        float wgt[4], lg[4];
        float m = -1e30f;
#pragma unroll
        for (int kk = 0; kk < 4; ++kk) {
            float ox = off_s[t * 64 + (h * 4 + kk) * 2];
            float oy = off_s[t * 64 + (h * 4 + kk) * 2 + 1];
            float cx = rp.x + ox - 0.5f, cy = rp.y + oy - 0.5f;
            float wx = fmaxf(0.f, 1.f - fabsf(cx));
            float wy = fmaxf(0.f, 1.f - fabsf(cy));
            wgt[kk] = wx * wy;
            lg[kk] = qk * wgt[kk] * 0.17677669529663687f;  // 1/sqrt(32)
            m = fmaxf(m, lg[kk]);
        }
        float s = 0.f, sw = 0.f;
#pragma unroll
        for (int kk = 0; kk < 4; ++kk) {
            float e = __expf(lg[kk] - m);
            s += e;
            sw += e * wgt[kk];
        }
        wv_s[t * 8 + h] = sw / s;
    }

    // ---------- phase 6: o = (value @ Wv + bv) * wv  -> Hb ----------
    stage(value);
    __syncthreads();
    zero_acc(acc);
    mfma_block<8>(Ab, WTv, 256, cb, 0, 0, acc, r16, q4);
#pragma unroll
    for (int mf = 0; mf < 4; ++mf)
#pragma unroll
        for (int nf = 0; nf < 4; ++nf) {
            int col = cb + nf * 16 + r16;
            float bias = bv[col];
            float wvv0 = wv_s[0];  // dummy to keep compiler happy on unroll (overwritten below)
            (void)wvv0;
#pragma unroll
            for (int r = 0; r < 4; ++r) {
                int row = mf * 16 + q4 * 4 + r;
                float wvv = wv_s[row * 8 + (col >> 5)];
                *(__bf16*)((char*)Hb + swz(row, col)) = (__bf16)((acc[mf][nf][r] + bias) * wvv);
            }
        }
    __syncthreads();

    // ---------- phase 7: out = o @ Wout + bout ----------
    zero_acc(acc);
    mfma_block<8>(Hb, WTout, 256, cb, 0, 0, acc, r16, q4);
#pragma unroll
    for (int mf = 0; mf < 4; ++mf)
#pragma unroll
        for (int nf = 0; nf < 4; ++nf) {
            int col = cb + nf * 16 + r16;
            float bias = bout[col];
#pragma unroll
            for (int r = 0; r < 4; ++r) {
                int row = mf * 16 + q4 * 4 + r;
                out[(size_t)(row0 + row) * CC + col] = acc[mf][nf][r] + bias;
            }
        }
}

extern "C" void kernel_launch(void* const* d_in, const int* in_sizes, int n_in,
                              void* d_out, int out_size, void* d_ws, size_t ws_size,
                              hipStream_t stream)
{
    const float* query = (const float*)d_in[0];
    const float* key   = (const float*)d_in[1];
    const float* value = (const float*)d_in[2];
    const float* refp  = (const float*)d_in[3];
    const float* pose  = (const float*)d_in[4];
    const float* Wq  = (const float*)d_in[5];  const float* bq   = (const float*)d_in[6];
    const float* Wk  = (const float*)d_in[7];  const float* bk   = (const float*)d_in[8];
    const float* Wv  = (const float*)d_in[9];  const float* bv   = (const float*)d_in[10];
    const float* Wo1 = (const float*)d_in[11]; const float* bo1  = (const float*)d_in[12];
    const float* Wo2 = (const float*)d_in[13]; const float* bo2  = (const float*)d_in[14];
    const float* Wpos= (const float*)d_in[15]; const float* bpos = (const float*)d_in[16];
    const float* Wout= (const float*)d_in[17]; const float* bout = (const float*)d_in[18];

    __bf16* ws = (__bf16*)d_ws;
    __bf16* WTq   = ws;            // [256][256]
    __bf16* WTk   = ws + 65536;    // [256][256]
    __bf16* WTv   = ws + 131072;   // [256][256]
    __bf16* WTpos = ws + 196608;   // [256][256]
    __bf16* WTo1  = ws + 262144;   // [512][256]
    __bf16* WTo2  = ws + 393216;   // [64][512]
    __bf16* WTout = ws + 425984;   // [256][256]

    prep_wt<<<256, 256, 0, stream>>>(Wq,   WTq,   256, 256);
    prep_wt<<<256, 256, 0, stream>>>(Wk,   WTk,   256, 256);
    prep_wt<<<256, 256, 0, stream>>>(Wv,   WTv,   256, 256);
    prep_wt<<<256, 256, 0, stream>>>(Wpos, WTpos, 256, 256);
    prep_wt<<<512, 256, 0, stream>>>(Wo1,  WTo1,  256, 512);
    prep_wt<<<128, 256, 0, stream>>>(Wo2,  WTo2,  512, 64);
    prep_wt<<<256, 256, 0, stream>>>(Wout, WTout, 256, 256);

    fused_ext_attn<<<65536 / MT, 256, 0, stream>>>(
        query, key, value, refp, pose,
        WTq, WTk, WTv, WTpos, WTo1, WTo2, WTout,
        bq, bk, bv, bpos, bo1, bo2, bout,
        (float*)d_out);
}